// Round 1
// baseline (125.157 us; speedup 1.0000x reference)
//
#include <hip/hip_runtime.h>
#include <math.h>

// Problem constants (fixed shapes from reference)
#define N_  4
#define C_  64
#define H_  28
#define W_  28
#define F_  64
#define KK  576          // C_ * 3 * 3
#define NX  (N_*C_*H_*W_)   // 200704

// ws float layout:
// [0..63]    partial min of x (64 blocks)
// [64..127]  partial max of x
// [128]      scale_x
// [129]      zp_x
// [256..]    Wt[576*64]  dequantized W, transposed: Wt[k*64 + f]

__global__ void k_minmax(const float* __restrict__ x, float* __restrict__ ws) {
  __shared__ float sm[4], sM[4];
  int tid = threadIdx.x;
  int gid = blockIdx.x * 256 + tid;
  float m = 3.4e38f, M = -3.4e38f;
  for (int i = gid; i < NX; i += 64 * 256) {
    float v = x[i];
    m = fminf(m, v);
    M = fmaxf(M, v);
  }
  #pragma unroll
  for (int o = 32; o; o >>= 1) {
    m = fminf(m, __shfl_xor(m, o));
    M = fmaxf(M, __shfl_xor(M, o));
  }
  if ((tid & 63) == 0) { sm[tid >> 6] = m; sM[tid >> 6] = M; }
  __syncthreads();
  if (tid == 0) {
    m = fminf(fminf(sm[0], sm[1]), fminf(sm[2], sm[3]));
    M = fmaxf(fmaxf(sM[0], sM[1]), fmaxf(sM[2], sM[3]));
    ws[blockIdx.x] = m;
    ws[64 + blockIdx.x] = M;
  }
}

__global__ void k_prep(const float* __restrict__ Wg, float* __restrict__ ws) {
  __shared__ float sw[64], zw[64];
  int tid = threadIdx.x, lane = tid & 63, wv = tid >> 6;

  // Phase 1: finalize global x min/max -> scale/zp (wave 0 only)
  if (tid < 64) {
    float m = ws[tid], M = ws[64 + tid];
    #pragma unroll
    for (int o = 32; o; o >>= 1) {
      m = fminf(m, __shfl_xor(m, o));
      M = fmaxf(M, __shfl_xor(M, o));
    }
    if (tid == 0) {
      float s = fmaxf((M - m) / 65535.0f, 1e-12f);
      float z = rintf(-m / s);
      ws[128] = s;
      ws[129] = z;
    }
  }

  // Phase 2: per-channel W min/max -> scale/zp (wave wv handles 16 channels)
  for (int t = 0; t < 16; ++t) {
    int ch = wv * 16 + t;
    const float* wp = Wg + ch * KK;
    float m = 3.4e38f, M = -3.4e38f;
    #pragma unroll
    for (int u = 0; u < 9; ++u) {           // 576 = 9 * 64 exactly
      float v = wp[lane + 64 * u];
      m = fminf(m, v);
      M = fmaxf(M, v);
    }
    #pragma unroll
    for (int o = 32; o; o >>= 1) {
      m = fminf(m, __shfl_xor(m, o));
      M = fmaxf(M, __shfl_xor(M, o));
    }
    if (lane == 0) {
      float s = fmaxf((M - m) / 255.0f, 1e-12f);
      sw[ch] = s;
      zw[ch] = rintf(-m / s);
    }
  }
  __syncthreads();

  // Phase 3: dequantize + transpose W into ws (coalesced writes)
  float* Wt = ws + 256;
  for (int idx = tid; idx < KK * 64; idx += 256) {
    int f = idx & 63, e = idx >> 6;
    float raw = Wg[f * KK + e];
    float s = sw[f], z = zw[f];
    float q = fminf(fmaxf(rintf(raw / s) + z, 0.0f), 255.0f);
    Wt[idx] = (q - z) * s;
  }
}

// Block: (y, n, f-half). Threads: 256 = 32 f x 8 col-groups (7 active, 4 cols each).
__global__ __launch_bounds__(256) void k_main(const float* __restrict__ x,
                                              const float* __restrict__ ws,
                                              float* __restrict__ out) {
  __shared__ float Xs[64 * 3 * 32];   // quantized x: [c][r=y-1..y+1][p=col+1, 0..29], stride 32
  __shared__ float Wl[144 * 64];      // 16-channel W chunk, [k_local][f]
  int tid = threadIdx.x;
  int y = blockIdx.x, n = blockIdx.y, fh = blockIdx.z;

  float sx = ws[128], zx = ws[129];

  // Stage quantized X (zero padding applied AFTER quantization, per reference)
  for (int idx = tid; idx < 64 * 3 * 30; idx += 256) {
    int c = idx / 90, rem = idx - c * 90;
    int r = rem / 30, p = rem - r * 30;
    int row = y + r - 1, col = p - 1;
    float v = 0.0f;
    if ((unsigned)row < 28u && (unsigned)col < 28u) {
      float raw = x[((n * 64 + c) * 28 + row) * 28 + col];
      float q = fminf(fmaxf(rintf(raw / sx) + zx, 0.0f), 65535.0f);
      v = (q - zx) * sx;
    }
    Xs[(c * 3 + r) * 32 + p] = v;
  }

  const float* Wt = ws + 256;
  int f_l = tid & 31, g = tid >> 5;
  int f = fh * 32 + f_l;
  int base = g * 4;                    // 0,4,...,28 (g==7 idle)
  bool active = (base < 28);
  float acc0 = 0.f, acc1 = 0.f, acc2 = 0.f, acc3 = 0.f;

  for (int cc = 0; cc < 4; ++cc) {
    __syncthreads();
    // stage 16-channel W chunk (coalesced float4 copy from L2-resident ws)
    const float4* src = (const float4*)(Wt + cc * 9216);
    float4* dst = (float4*)Wl;
    for (int i4 = tid; i4 < 2304; i4 += 256) dst[i4] = src[i4];
    __syncthreads();

    if (active) {
      #pragma unroll 4
      for (int c2 = 0; c2 < 16; ++c2) {
        const float* xr = &Xs[((cc * 16 + c2) * 3) * 32 + base];
        float xv0[6], xv1[6], xv2[6];
        #pragma unroll
        for (int p = 0; p < 6; ++p) {
          xv0[p] = xr[p];
          xv1[p] = xr[32 + p];
          xv2[p] = xr[64 + p];
        }
        const float* wr = &Wl[(c2 * 9) * 64 + f];
        #pragma unroll
        for (int j = 0; j < 3; ++j) {
          float w0 = wr[j * 64], w1 = wr[(3 + j) * 64], w2 = wr[(6 + j) * 64];
          acc0 += fabsf(w0 - xv0[j])     + fabsf(w1 - xv1[j])     + fabsf(w2 - xv2[j]);
          acc1 += fabsf(w0 - xv0[1 + j]) + fabsf(w1 - xv1[1 + j]) + fabsf(w2 - xv2[1 + j]);
          acc2 += fabsf(w0 - xv0[2 + j]) + fabsf(w1 - xv1[2 + j]) + fabsf(w2 - xv2[2 + j]);
          acc3 += fabsf(w0 - xv0[3 + j]) + fabsf(w1 - xv1[3 + j]) + fabsf(w2 - xv2[3 + j]);
        }
      }
    }
  }

  if (active) {
    float* o = out + ((n * 64 + f) * 28 + y) * 28 + base;
    o[0] = -acc0; o[1] = -acc1; o[2] = -acc2; o[3] = -acc3;
  }
}

extern "C" void kernel_launch(void* const* d_in, const int* in_sizes, int n_in,
                              void* d_out, int out_size, void* d_ws, size_t ws_size,
                              hipStream_t stream) {
  const float* x  = (const float*)d_in[0];
  const float* Wg = (const float*)d_in[1];
  float* out = (float*)d_out;
  float* ws  = (float*)d_ws;

  hipLaunchKernelGGL(k_minmax, dim3(64), dim3(256), 0, stream, x, ws);
  hipLaunchKernelGGL(k_prep,   dim3(1),  dim3(256), 0, stream, Wg, ws);
  hipLaunchKernelGGL(k_main,   dim3(28, 4, 2), dim3(256), 0, stream, x, ws, out);
}

// Round 2
// 90.401 us; speedup vs baseline: 1.3845x; 1.3845x over previous
//
#include <hip/hip_runtime.h>
#include <math.h>

// Problem constants (fixed shapes from reference)
#define N_  4
#define C_  64
#define H_  28
#define W_  28
#define F_  64
#define KK  576            // C_ * 3 * 3
#define NX  (N_*C_*H_*W_)  // 200704
#define NX4 (NX/4)         // 50176 float4s

// ws float layout:
// [0..63]   per-block partial min of x
// [64..127] per-block partial max of x

// ---------------------------------------------------------------------------
// Kernel 1: partial min/max of x (64 blocks x 256 threads, float4 loads)
// ---------------------------------------------------------------------------
__global__ __launch_bounds__(256) void k_minmax(const float* __restrict__ x,
                                                float* __restrict__ ws) {
  __shared__ float sm[4], sM[4];
  int tid = threadIdx.x;
  int gid = blockIdx.x * 256 + tid;
  const float4* x4 = (const float4*)x;
  float m = 3.4e38f, M = -3.4e38f;
  for (int i = gid; i < NX4; i += 64 * 256) {
    float4 v = x4[i];
    m = fminf(m, fminf(fminf(v.x, v.y), fminf(v.z, v.w)));
    M = fmaxf(M, fmaxf(fmaxf(v.x, v.y), fmaxf(v.z, v.w)));
  }
  #pragma unroll
  for (int o = 32; o; o >>= 1) {
    m = fminf(m, __shfl_xor(m, o));
    M = fmaxf(M, __shfl_xor(M, o));
  }
  if ((tid & 63) == 0) { sm[tid >> 6] = m; sM[tid >> 6] = M; }
  __syncthreads();
  if (tid == 0) {
    m = fminf(fminf(sm[0], sm[1]), fminf(sm[2], sm[3]));
    M = fmaxf(fmaxf(sM[0], sM[1]), fmaxf(sM[2], sM[3]));
    ws[blockIdx.x] = m;
    ws[64 + blockIdx.x] = M;
  }
}

// ---------------------------------------------------------------------------
// Kernel 2: everything else. Grid (y=28, n=4, fh=2), block 256 (4 waves).
//   Per block: finalize x scale/zp (register butterfly, no barrier),
//   stage quantized X rows y-1..y+1 in LDS, per-filter W quant+dequant into
//   LDS (each wave owns 8 filters), ONE barrier, then the L1-distance loop.
// ---------------------------------------------------------------------------
__global__ __launch_bounds__(256) void k_main(const float* __restrict__ x,
                                              const float* __restrict__ Wg,
                                              const float* __restrict__ ws,
                                              float* __restrict__ out) {
  // Xs: quantized x, [c][r=y-1..y+1][p=col+1 in 0..29], row stride 32 (16B align ok)
  __shared__ __align__(16) float Xs[64 * 3 * 32];     // 24 KB
  // Wl: dequantized W for this block's 32 filters, [k][fl] padded: k*33+fl
  __shared__ __align__(16) float Wl[KK * 33];          // 76 KB
  int tid  = threadIdx.x;
  int lane = tid & 63, wv = tid >> 6;
  int y = blockIdx.x, n = blockIdx.y, fh = blockIdx.z;

  // --- Phase A: global x scale/zp, per-wave redundant butterfly (no barrier)
  float m = ws[lane], M = ws[64 + lane];
  #pragma unroll
  for (int o = 32; o; o >>= 1) {
    m = fminf(m, __shfl_xor(m, o));
    M = fmaxf(M, __shfl_xor(M, o));
  }
  float sx = fmaxf((M - m) / 65535.0f, 1e-12f);
  float zx = rintf(-m / sx);

  // --- Phase B: stage quantized X (zero padding applied AFTER quantization)
  for (int idx = tid; idx < 64 * 3 * 30; idx += 256) {
    int c = idx / 90, rem = idx - c * 90;
    int r = rem / 30, p = rem - r * 30;
    int row = y + r - 1, col = p - 1;
    float v = 0.0f;
    if ((unsigned)row < 28u && (unsigned)col < 28u) {
      float raw = x[((n * 64 + c) * 28 + row) * 28 + col];
      float q = fminf(fmaxf(rintf(raw / sx) + zx, 0.0f), 65535.0f);
      v = (q - zx) * sx;
    }
    Xs[(c * 3 + r) * 32 + p] = v;
  }

  // --- Phase C: per-filter W fake-quant + dequant into LDS (wave wv: 8 filters)
  for (int t = 0; t < 8; ++t) {
    int fl = wv * 8 + t;                 // 0..31 within block
    int fg = fh * 32 + fl;               // global filter
    const float* wp = Wg + fg * KK;
    float v[9];
    float wm = 3.4e38f, wM = -3.4e38f;
    #pragma unroll
    for (int u = 0; u < 9; ++u) {        // 576 = 9*64, coalesced
      v[u] = wp[lane + 64 * u];
      wm = fminf(wm, v[u]);
      wM = fmaxf(wM, v[u]);
    }
    #pragma unroll
    for (int o = 32; o; o >>= 1) {
      wm = fminf(wm, __shfl_xor(wm, o));
      wM = fmaxf(wM, __shfl_xor(wM, o));
    }
    float s = fmaxf((wM - wm) / 255.0f, 1e-12f);
    float z = rintf(-wm / s);
    #pragma unroll
    for (int u = 0; u < 9; ++u) {
      float q = fminf(fmaxf(rintf(v[u] / s) + z, 0.0f), 255.0f);
      Wl[(lane + 64 * u) * 33 + fl] = (q - z) * s;   // banks (k+f)%32: conflict-free
    }
  }

  __syncthreads();   // the only barrier

  // --- Phase D: L1-distance main loop. Thread = (fl in 0..31, g in 0..7),
  //     g<7 active, computes 4 output cols base..base+3.
  int fl = tid & 31, g = tid >> 5;
  int base = g * 4;
  bool active = (base < 28);
  float acc0 = 0.f, acc1 = 0.f, acc2 = 0.f, acc3 = 0.f;

  if (active) {
    const float* xb = &Xs[base];
    const float* wb = &Wl[fl];
    for (int c = 0; c < 64; ++c) {
      const float* xr = xb + c * 96;
      float4 a0 = *(const float4*)(xr);        // row y-1, cols base..base+3
      float4 a1 = *(const float4*)(xr + 4);    //             base+4..base+7
      float4 b0 = *(const float4*)(xr + 32);   // row y
      float4 b1 = *(const float4*)(xr + 36);
      float4 c0 = *(const float4*)(xr + 64);   // row y+1
      float4 c1 = *(const float4*)(xr + 68);
      const float* wr = wb + c * 297;          // 9*33
      float w0 = wr[0],   w1 = wr[33],  w2 = wr[66];
      float w3 = wr[99],  w4 = wr[132], w5 = wr[165];
      float w6 = wr[198], w7 = wr[231], w8 = wr[264];

      acc0 += fabsf(w0 - a0.x) + fabsf(w1 - a0.y) + fabsf(w2 - a0.z)
            + fabsf(w3 - b0.x) + fabsf(w4 - b0.y) + fabsf(w5 - b0.z)
            + fabsf(w6 - c0.x) + fabsf(w7 - c0.y) + fabsf(w8 - c0.z);
      acc1 += fabsf(w0 - a0.y) + fabsf(w1 - a0.z) + fabsf(w2 - a0.w)
            + fabsf(w3 - b0.y) + fabsf(w4 - b0.z) + fabsf(w5 - b0.w)
            + fabsf(w6 - c0.y) + fabsf(w7 - c0.z) + fabsf(w8 - c0.w);
      acc2 += fabsf(w0 - a0.z) + fabsf(w1 - a0.w) + fabsf(w2 - a1.x)
            + fabsf(w3 - b0.z) + fabsf(w4 - b0.w) + fabsf(w5 - b1.x)
            + fabsf(w6 - c0.z) + fabsf(w7 - c0.w) + fabsf(w8 - c1.x);
      acc3 += fabsf(w0 - a0.w) + fabsf(w1 - a1.x) + fabsf(w2 - a1.y)
            + fabsf(w3 - b0.w) + fabsf(w4 - b1.x) + fabsf(w5 - b1.y)
            + fabsf(w6 - c0.w) + fabsf(w7 - c1.x) + fabsf(w8 - c1.y);
    }
    int f = fh * 32 + fl;
    float4* o = (float4*)(out + ((n * 64 + f) * 28 + y) * 28 + base);
    *o = make_float4(-acc0, -acc1, -acc2, -acc3);
  }
}

extern "C" void kernel_launch(void* const* d_in, const int* in_sizes, int n_in,
                              void* d_out, int out_size, void* d_ws, size_t ws_size,
                              hipStream_t stream) {
  const float* x  = (const float*)d_in[0];
  const float* Wg = (const float*)d_in[1];
  float* out = (float*)d_out;
  float* ws  = (float*)d_ws;

  hipLaunchKernelGGL(k_minmax, dim3(64), dim3(256), 0, stream, x, ws);
  hipLaunchKernelGGL(k_main, dim3(28, 4, 2), dim3(256), 0, stream, x, Wg, ws, out);
}

// Round 3
// 85.478 us; speedup vs baseline: 1.4642x; 1.0576x over previous
//
#include <hip/hip_runtime.h>
#include <math.h>

// Problem constants (fixed shapes from reference)
#define N_  4
#define C_  64
#define H_  28
#define W_  28
#define F_  64
#define KK  576            // C_ * 3 * 3
#define NX  (N_*C_*H_*W_)  // 200704
#define NX4 (NX/4)         // 50176 float4s

// ws float layout:
// [0..63]    per-block partial min of x
// [64..127]  per-block partial max of x
// [256..]    Wt[576*64]  dequantized W, k-major: Wt[k*64 + f]

// ---------------------------------------------------------------------------
// Kernel 1: grid 64 x 256.
//   All blocks: partial min/max of x (float4).
//   Blocks 0..15 additionally: fake-quant+dequant 4 filters (1 per wave),
//   write k-major Wt into ws.
// ---------------------------------------------------------------------------
__global__ __launch_bounds__(256) void k_prep(const float* __restrict__ x,
                                              const float* __restrict__ Wg,
                                              float* __restrict__ ws) {
  __shared__ float sm[4], sM[4];
  int tid = threadIdx.x, lane = tid & 63, wv = tid >> 6;

  // --- x min/max partial ---
  const float4* x4 = (const float4*)x;
  float m = 3.4e38f, M = -3.4e38f;
  for (int i = blockIdx.x * 256 + tid; i < NX4; i += 64 * 256) {
    float4 v = x4[i];
    m = fminf(m, fminf(fminf(v.x, v.y), fminf(v.z, v.w)));
    M = fmaxf(M, fmaxf(fmaxf(v.x, v.y), fmaxf(v.z, v.w)));
  }
  #pragma unroll
  for (int o = 32; o; o >>= 1) {
    m = fminf(m, __shfl_xor(m, o));
    M = fmaxf(M, __shfl_xor(M, o));
  }
  if (lane == 0) { sm[wv] = m; sM[wv] = M; }
  __syncthreads();
  if (tid == 0) {
    m = fminf(fminf(sm[0], sm[1]), fminf(sm[2], sm[3]));
    M = fmaxf(fmaxf(sM[0], sM[1]), fmaxf(sM[2], sM[3]));
    ws[blockIdx.x] = m;
    ws[64 + blockIdx.x] = M;
  }

  // --- W fake-quant + dequant, k-major transpose (blocks 0..15, wave = filter) ---
  if (blockIdx.x < 16) {
    int f = blockIdx.x * 4 + wv;
    const float* wp = Wg + f * KK;
    float v[9];
    float wm = 3.4e38f, wM = -3.4e38f;
    #pragma unroll
    for (int u = 0; u < 9; ++u) {
      v[u] = wp[lane + 64 * u];
      wm = fminf(wm, v[u]);
      wM = fmaxf(wM, v[u]);
    }
    #pragma unroll
    for (int o = 32; o; o >>= 1) {
      wm = fminf(wm, __shfl_xor(wm, o));
      wM = fmaxf(wM, __shfl_xor(wM, o));
    }
    float s = fmaxf((wM - wm) / 255.0f, 1e-12f);
    float z = rintf(-wm / s);
    float rs = 1.0f / s;
    float* Wt = ws + 256;
    #pragma unroll
    for (int u = 0; u < 9; ++u) {
      float q = fminf(fmaxf(rintf(v[u] * rs) + z, 0.0f), 255.0f);
      Wt[(lane + 64 * u) * 64 + f] = (q - z) * s;
    }
  }
}

// ---------------------------------------------------------------------------
// Kernel 2: grid (y=28, n=4, fh=2), 256 threads.
//   A: finalize x scale/zp (register butterfly, no barrier)
//   B: stage quantized X rows y-1..y+1 in LDS
//   C: burst-copy this block's 32 filters of Wt into LDS (no math)
//   one barrier, then D: the L1-distance loop.
// ---------------------------------------------------------------------------
__global__ __launch_bounds__(256) void k_main(const float* __restrict__ x,
                                              const float* __restrict__ ws,
                                              float* __restrict__ out) {
  __shared__ __align__(16) float Xs[64 * 3 * 32];   // 24 KB
  __shared__ __align__(16) float Wl[KK * 33];       // 76 KB, [k]*33+[fl]
  int tid  = threadIdx.x;
  int lane = tid & 63;
  int y = blockIdx.x, n = blockIdx.y, fh = blockIdx.z;

  // --- Phase A ---
  float m = ws[lane], M = ws[64 + lane];
  #pragma unroll
  for (int o = 32; o; o >>= 1) {
    m = fminf(m, __shfl_xor(m, o));
    M = fmaxf(M, __shfl_xor(M, o));
  }
  float sx = fmaxf((M - m) / 65535.0f, 1e-12f);
  float zx = rintf(-m / sx);
  float rx = 1.0f / sx;

  // --- Phase B: stage quantized X (padding applied AFTER quantization) ---
  for (int idx = tid; idx < 64 * 3 * 30; idx += 256) {
    int c = idx / 90, rem = idx - c * 90;
    int r = rem / 30, p = rem - r * 30;
    int row = y + r - 1, col = p - 1;
    float v = 0.0f;
    if ((unsigned)row < 28u && (unsigned)col < 28u) {
      float raw = x[((n * 64 + c) * 28 + row) * 28 + col];
      float q = fminf(fmaxf(rintf(raw * rx) + zx, 0.0f), 65535.0f);
      v = (q - zx) * sx;
    }
    Xs[(c * 3 + r) * 32 + p] = v;
  }

  // --- Phase C: burst copy Wt columns [fh*32, fh*32+32) into Wl[k*33+fl] ---
  {
    const float4* Wt4 = (const float4*)(ws + 256);   // [k][16 float4s]
    #pragma unroll
    for (int i = 0; i < 18; ++i) {                   // 4608 float4 = 256*18
      int idx = tid + 256 * i;
      int k = idx >> 3, q = idx & 7;
      float4 v = Wt4[k * 16 + fh * 8 + q];
      float* d = &Wl[k * 33 + q * 4];
      d[0] = v.x; d[1] = v.y; d[2] = v.z; d[3] = v.w;
    }
  }

  __syncthreads();   // the only barrier

  // --- Phase D ---
  int fl = tid & 31, g = tid >> 5;
  int base = g * 4;
  bool active = (base < 28);
  float acc0 = 0.f, acc1 = 0.f, acc2 = 0.f, acc3 = 0.f;

  if (active) {
    const float* xb = &Xs[base];
    const float* wb = &Wl[fl];
    #pragma unroll 2
    for (int c = 0; c < 64; ++c) {
      const float* xr = xb + c * 96;
      float4 a0 = *(const float4*)(xr);
      float4 a1 = *(const float4*)(xr + 4);
      float4 b0 = *(const float4*)(xr + 32);
      float4 b1 = *(const float4*)(xr + 36);
      float4 c0 = *(const float4*)(xr + 64);
      float4 c1 = *(const float4*)(xr + 68);
      const float* wr = wb + c * 297;                // 9*33
      float w0 = wr[0],   w1 = wr[33],  w2 = wr[66];
      float w3 = wr[99],  w4 = wr[132], w5 = wr[165];
      float w6 = wr[198], w7 = wr[231], w8 = wr[264];

      acc0 += fabsf(w0 - a0.x) + fabsf(w1 - a0.y) + fabsf(w2 - a0.z)
            + fabsf(w3 - b0.x) + fabsf(w4 - b0.y) + fabsf(w5 - b0.z)
            + fabsf(w6 - c0.x) + fabsf(w7 - c0.y) + fabsf(w8 - c0.z);
      acc1 += fabsf(w0 - a0.y) + fabsf(w1 - a0.z) + fabsf(w2 - a0.w)
            + fabsf(w3 - b0.y) + fabsf(w4 - b0.z) + fabsf(w5 - b0.w)
            + fabsf(w6 - c0.y) + fabsf(w7 - c0.z) + fabsf(w8 - c0.w);
      acc2 += fabsf(w0 - a0.z) + fabsf(w1 - a0.w) + fabsf(w2 - a1.x)
            + fabsf(w3 - b0.z) + fabsf(w4 - b0.w) + fabsf(w5 - b1.x)
            + fabsf(w6 - c0.z) + fabsf(w7 - c0.w) + fabsf(w8 - c1.x);
      acc3 += fabsf(w0 - a0.w) + fabsf(w1 - a1.x) + fabsf(w2 - a1.y)
            + fabsf(w3 - b0.w) + fabsf(w4 - b1.x) + fabsf(w5 - b1.y)
            + fabsf(w6 - c0.w) + fabsf(w7 - c1.x) + fabsf(w8 - c1.y);
    }
    int f = fh * 32 + fl;
    float4* o = (float4*)(out + ((n * 64 + f) * 28 + y) * 28 + base);
    *o = make_float4(-acc0, -acc1, -acc2, -acc3);
  }
}

extern "C" void kernel_launch(void* const* d_in, const int* in_sizes, int n_in,
                              void* d_out, int out_size, void* d_ws, size_t ws_size,
                              hipStream_t stream) {
  const float* x  = (const float*)d_in[0];
  const float* Wg = (const float*)d_in[1];
  float* out = (float*)d_out;
  float* ws  = (float*)d_ws;

  hipLaunchKernelGGL(k_prep, dim3(64), dim3(256), 0, stream, x, Wg, ws);
  hipLaunchKernelGGL(k_main, dim3(28, 4, 2), dim3(256), 0, stream, x, ws, out);
}

// Round 4
// 82.496 us; speedup vs baseline: 1.5171x; 1.0361x over previous
//
#include <hip/hip_runtime.h>
#include <math.h>

// Problem constants (fixed shapes from reference)
#define N_  4
#define C_  64
#define H_  28
#define W_  28
#define F_  64
#define KK  576            // C_ * 3 * 3
#define NX  (N_*C_*H_*W_)  // 200704
#define NX4 (NX/4)         // 50176 float4s

// ws float layout:
// [0..63]    per-block partial min of x
// [64..127]  per-block partial max of x
// [256..]    Wt[576*64]  dequantized W, k-major: Wt[(c*9+k)*64 + f]

// ---------------------------------------------------------------------------
// Kernel 1: grid 64 x 256.
//   All blocks: partial min/max of x (float4).
//   Blocks 0..15 additionally: fake-quant+dequant 4 filters (1 per wave),
//   write k-major Wt into ws.
// ---------------------------------------------------------------------------
__global__ __launch_bounds__(256) void k_prep(const float* __restrict__ x,
                                              const float* __restrict__ Wg,
                                              float* __restrict__ ws) {
  __shared__ float sm[4], sM[4];
  int tid = threadIdx.x, lane = tid & 63, wv = tid >> 6;

  const float4* x4 = (const float4*)x;
  float m = 3.4e38f, M = -3.4e38f;
  for (int i = blockIdx.x * 256 + tid; i < NX4; i += 64 * 256) {
    float4 v = x4[i];
    m = fminf(m, fminf(fminf(v.x, v.y), fminf(v.z, v.w)));
    M = fmaxf(M, fmaxf(fmaxf(v.x, v.y), fmaxf(v.z, v.w)));
  }
  #pragma unroll
  for (int o = 32; o; o >>= 1) {
    m = fminf(m, __shfl_xor(m, o));
    M = fmaxf(M, __shfl_xor(M, o));
  }
  if (lane == 0) { sm[wv] = m; sM[wv] = M; }
  __syncthreads();
  if (tid == 0) {
    m = fminf(fminf(sm[0], sm[1]), fminf(sm[2], sm[3]));
    M = fmaxf(fmaxf(sM[0], sM[1]), fmaxf(sM[2], sM[3]));
    ws[blockIdx.x] = m;
    ws[64 + blockIdx.x] = M;
  }

  if (blockIdx.x < 16) {
    int f = blockIdx.x * 4 + wv;
    const float* wp = Wg + f * KK;
    float v[9];
    float wm = 3.4e38f, wM = -3.4e38f;
    #pragma unroll
    for (int u = 0; u < 9; ++u) {
      v[u] = wp[lane + 64 * u];
      wm = fminf(wm, v[u]);
      wM = fmaxf(wM, v[u]);
    }
    #pragma unroll
    for (int o = 32; o; o >>= 1) {
      wm = fminf(wm, __shfl_xor(wm, o));
      wM = fmaxf(wM, __shfl_xor(wM, o));
    }
    float s = fmaxf((wM - wm) / 255.0f, 1e-12f);
    float z = rintf(-wm / s);
    float rs = 1.0f / s;
    float* Wt = ws + 256;
    #pragma unroll
    for (int u = 0; u < 9; ++u) {
      float q = fminf(fmaxf(rintf(v[u] * rs) + z, 0.0f), 255.0f);
      Wt[(lane + 64 * u) * 64 + f] = (q - z) * s;
    }
  }
}

// ---------------------------------------------------------------------------
// Kernel 2: grid (y=28, n=4, fh=2), 256 threads = 32 filters x 8 channel-octets.
//   Each thread: filter f = fh*32+fl, channels cq*8..cq*8+7, ALL 28 cols.
//   W read straight from L2 (coalesced, double-prefetched) - never in LDS.
//   X read from LDS via broadcast. Partials over cq reduced through LDS.
// ---------------------------------------------------------------------------
__global__ __launch_bounds__(256, 1) void k_main(const float* __restrict__ x,
                                                 const float* __restrict__ ws,
                                                 float* __restrict__ out) {
  __shared__ __align__(16) float Xs[64 * 3 * 32];  // 24 KB quantized x
  __shared__ float Rbuf[8 * 32 * 29];              // 29 KB partial sums [cq][fl][col]
  int tid = threadIdx.x;
  int lane = tid & 63;
  int fl = tid & 31, cq = tid >> 5;
  int y = blockIdx.x, n = blockIdx.y, fh = blockIdx.z;

  // --- Phase A: x scale/zp (register butterfly, no barrier) ---
  float m = ws[lane], M = ws[64 + lane];
  #pragma unroll
  for (int o = 32; o; o >>= 1) {
    m = fminf(m, __shfl_xor(m, o));
    M = fmaxf(M, __shfl_xor(M, o));
  }
  float sx = fmaxf((M - m) / 65535.0f, 1e-12f);
  float zx = rintf(-m / sx);
  float rx = 1.0f / sx;

  // --- Phase B: stage quantized X rows y-1..y+1 (padding AFTER quantization) ---
  for (int idx = tid; idx < 64 * 3 * 30; idx += 256) {
    int c = idx / 90, rem = idx - c * 90;
    int r = rem / 30, p = rem - r * 30;
    int row = y + r - 1, col = p - 1;
    float v = 0.0f;
    if ((unsigned)row < 28u && (unsigned)col < 28u) {
      float raw = x[((n * 64 + c) * 28 + row) * 28 + col];
      float q = fminf(fmaxf(rintf(raw * rx) + zx, 0.0f), 65535.0f);
      v = (q - zx) * sx;
    }
    Xs[(c * 3 + r) * 32 + p] = v;
  }
  __syncthreads();

  // --- Phase C: main loop. w from L2 (coalesced), X broadcast from LDS. ---
  const float* Wt = ws + 256;
  int f = fh * 32 + fl;
  float acc[28];
  #pragma unroll
  for (int i = 0; i < 28; ++i) acc[i] = 0.0f;

  float w[9], wn[9];
  {
    const float* wp = Wt + (cq * 8) * 9 * 64 + f;
    #pragma unroll
    for (int k = 0; k < 9; ++k) wn[k] = wp[k * 64];
  }
  for (int ci = 0; ci < 8; ++ci) {
    #pragma unroll
    for (int k = 0; k < 9; ++k) w[k] = wn[k];
    if (ci < 7) {
      const float* wp = Wt + (cq * 8 + ci + 1) * 9 * 64 + f;
      #pragma unroll
      for (int k = 0; k < 9; ++k) wn[k] = wp[k * 64];
    }
    const float* xr = &Xs[(cq * 8 + ci) * 96];
    #pragma unroll
    for (int p = 0; p < 28; ++p) {
      float s0 = fabsf(w[0] - xr[p])      + fabsf(w[1] - xr[p + 1])  + fabsf(w[2] - xr[p + 2]);
      float s1 = fabsf(w[3] - xr[32 + p]) + fabsf(w[4] - xr[33 + p]) + fabsf(w[5] - xr[34 + p]);
      float s2 = fabsf(w[6] - xr[64 + p]) + fabsf(w[7] - xr[65 + p]) + fabsf(w[8] - xr[66 + p]);
      acc[p] += s0 + s1 + s2;
    }
  }

  // --- Phase E: reduce the 8 cq-partials per (filter, col) through LDS ---
  #pragma unroll
  for (int p = 0; p < 28; ++p) Rbuf[(cq * 32 + fl) * 29 + p] = acc[p];
  __syncthreads();

  // 896 outputs (32 f x 28 cols) / 256 threads
  for (int i = 0; i < 4; ++i) {
    int idx = tid + 256 * i;
    if (idx < 896) {
      int ff = idx / 28, col = idx - ff * 28;
      float s = 0.0f;
      #pragma unroll
      for (int q = 0; q < 8; ++q) s += Rbuf[(q * 32 + ff) * 29 + col];
      out[((n * 64 + fh * 32 + ff) * 28 + y) * 28 + col] = -s;
    }
  }
}

extern "C" void kernel_launch(void* const* d_in, const int* in_sizes, int n_in,
                              void* d_out, int out_size, void* d_ws, size_t ws_size,
                              hipStream_t stream) {
  const float* x  = (const float*)d_in[0];
  const float* Wg = (const float*)d_in[1];
  float* out = (float*)d_out;
  float* ws  = (float*)d_ws;

  hipLaunchKernelGGL(k_prep, dim3(64), dim3(256), 0, stream, x, Wg, ws);
  hipLaunchKernelGGL(k_main, dim3(28, 4, 2), dim3(256), 0, stream, x, ws, out);
}

// Round 5
// 80.582 us; speedup vs baseline: 1.5532x; 1.0238x over previous
//
#include <hip/hip_runtime.h>
#include <math.h>

// Problem constants (fixed shapes from reference)
#define N_  4
#define C_  64
#define H_  28
#define W_  28
#define F_  64
#define KK  576            // C_ * 3 * 3
#define NX  (N_*C_*H_*W_)  // 200704
#define NX4 (NX/4)         // 50176 float4s

#define CH_STRIDE 100      // Xs floats per channel: 3 rows x 32 + 4 pad; 100 % 32 == 4
                           // -> 4 distinct per-wave channel addrs hit disjoint bank quads

// ws float layout:
// [0..63]    per-block partial min of x
// [64..127]  per-block partial max of x
// [256..]    Wt[576*64]  dequantized W, k-major: Wt[(c*9+k)*64 + f]

// ---------------------------------------------------------------------------
// Kernel 1: grid 64 x 256.
//   All blocks: partial min/max of x (float4).
//   Blocks 0..15 additionally: fake-quant+dequant 4 filters (1 per wave),
//   write k-major Wt into ws.
// ---------------------------------------------------------------------------
__global__ __launch_bounds__(256) void k_prep(const float* __restrict__ x,
                                              const float* __restrict__ Wg,
                                              float* __restrict__ ws) {
  __shared__ float sm[4], sM[4];
  int tid = threadIdx.x, lane = tid & 63, wv = tid >> 6;

  const float4* x4 = (const float4*)x;
  float m = 3.4e38f, M = -3.4e38f;
  for (int i = blockIdx.x * 256 + tid; i < NX4; i += 64 * 256) {
    float4 v = x4[i];
    m = fminf(m, fminf(fminf(v.x, v.y), fminf(v.z, v.w)));
    M = fmaxf(M, fmaxf(fmaxf(v.x, v.y), fmaxf(v.z, v.w)));
  }
  #pragma unroll
  for (int o = 32; o; o >>= 1) {
    m = fminf(m, __shfl_xor(m, o));
    M = fmaxf(M, __shfl_xor(M, o));
  }
  if (lane == 0) { sm[wv] = m; sM[wv] = M; }
  __syncthreads();
  if (tid == 0) {
    m = fminf(fminf(sm[0], sm[1]), fminf(sm[2], sm[3]));
    M = fmaxf(fmaxf(sM[0], sM[1]), fmaxf(sM[2], sM[3]));
    ws[blockIdx.x] = m;
    ws[64 + blockIdx.x] = M;
  }

  if (blockIdx.x < 16) {
    int f = blockIdx.x * 4 + wv;
    const float* wp = Wg + f * KK;
    float v[9];
    float wm = 3.4e38f, wM = -3.4e38f;
    #pragma unroll
    for (int u = 0; u < 9; ++u) {
      v[u] = wp[lane + 64 * u];
      wm = fminf(wm, v[u]);
      wM = fmaxf(wM, v[u]);
    }
    #pragma unroll
    for (int o = 32; o; o >>= 1) {
      wm = fminf(wm, __shfl_xor(wm, o));
      wM = fmaxf(wM, __shfl_xor(wM, o));
    }
    float s = fmaxf((wM - wm) / 255.0f, 1e-12f);
    float z = rintf(-wm / s);
    float rs = 1.0f / s;
    float* Wt = ws + 256;
    #pragma unroll
    for (int u = 0; u < 9; ++u) {
      float q = fminf(fmaxf(rintf(v[u] * rs) + z, 0.0f), 255.0f);
      Wt[(lane + 64 * u) * 64 + f] = (q - z) * s;
    }
  }
}

// ---------------------------------------------------------------------------
// Kernel 2: grid (y=28, n=4, fh=2), 256 threads = 16 filters x 16 ch-quads.
//   Thread (fl, cq): filters f0 = fh*32+fl and f1 = f0+16 (2x X-reuse per
//   LDS read), channels c = cq + 16*ci (ci=0..3), all 28 cols.
//   W straight from L2 (coalesced, next-channel prefetch). X rows loaded as
//   conflict-free float4 from LDS. 16 cq-partials reduced through LDS.
// ---------------------------------------------------------------------------
__global__ __launch_bounds__(256, 1) void k_main(const float* __restrict__ x,
                                                 const float* __restrict__ ws,
                                                 float* __restrict__ out) {
  __shared__ __align__(16) float Xs[64 * CH_STRIDE];   // 25.6 KB quantized x
  __shared__ float Rbuf[16 * 32 * 29];                 // 59.4 KB [cq][f_local][col]
  int tid = threadIdx.x;
  int lane = tid & 63;
  int fl = tid & 15, cq = tid >> 4;
  int y = blockIdx.x, n = blockIdx.y, fh = blockIdx.z;

  // --- Phase A: x scale/zp (register butterfly, no barrier) ---
  float m = ws[lane], M = ws[64 + lane];
  #pragma unroll
  for (int o = 32; o; o >>= 1) {
    m = fminf(m, __shfl_xor(m, o));
    M = fmaxf(M, __shfl_xor(M, o));
  }
  float sx = fmaxf((M - m) / 65535.0f, 1e-12f);
  float zx = rintf(-m / sx);
  float rx = 1.0f / sx;

  // --- Phase B: stage quantized X rows y-1..y+1 (padding AFTER quantization) ---
  for (int idx = tid; idx < 64 * 3 * 30; idx += 256) {
    int c = idx / 90, rem = idx - c * 90;
    int r = rem / 30, p = rem - r * 30;
    int row = y + r - 1, col = p - 1;
    float v = 0.0f;
    if ((unsigned)row < 28u && (unsigned)col < 28u) {
      float raw = x[((n * 64 + c) * 28 + row) * 28 + col];
      float q = fminf(fmaxf(rintf(raw * rx) + zx, 0.0f), 65535.0f);
      v = (q - zx) * sx;
    }
    Xs[c * CH_STRIDE + r * 32 + p] = v;
  }
  __syncthreads();

  // --- Phase C: main loop ---
  const float* Wt = ws + 256;
  int f0 = fh * 32 + fl;                 // second filter is f0 + 16
  float acc0[28], acc1[28];
  #pragma unroll
  for (int i = 0; i < 28; ++i) { acc0[i] = 0.0f; acc1[i] = 0.0f; }

  float wc[18], wn[18];
  {
    const float* wp = Wt + (cq * 9) * 64 + f0;     // channel cq, k=0..8
    #pragma unroll
    for (int k = 0; k < 9; ++k) { wn[k] = wp[k * 64]; wn[9 + k] = wp[k * 64 + 16]; }
  }

  for (int ci = 0; ci < 4; ++ci) {
    #pragma unroll
    for (int k = 0; k < 18; ++k) wc[k] = wn[k];
    if (ci < 3) {
      int cn = cq + 16 * (ci + 1);
      const float* wp = Wt + (cn * 9) * 64 + f0;
      #pragma unroll
      for (int k = 0; k < 9; ++k) { wn[k] = wp[k * 64]; wn[9 + k] = wp[k * 64 + 16]; }
    }
    int c = cq + 16 * ci;
    #pragma unroll
    for (int r = 0; r < 3; ++r) {
      const float4* xr4 = (const float4*)&Xs[c * CH_STRIDE + r * 32];
      float xv[32];
      #pragma unroll
      for (int i = 0; i < 8; ++i) ((float4*)xv)[i] = xr4[i];
      float wa0 = wc[3 * r], wa1 = wc[3 * r + 1], wa2 = wc[3 * r + 2];
      float wb0 = wc[9 + 3 * r], wb1 = wc[9 + 3 * r + 1], wb2 = wc[9 + 3 * r + 2];
      #pragma unroll
      for (int p = 0; p < 28; ++p) {
        acc0[p] += fabsf(wa0 - xv[p]) + fabsf(wa1 - xv[p + 1]) + fabsf(wa2 - xv[p + 2]);
        acc1[p] += fabsf(wb0 - xv[p]) + fabsf(wb1 - xv[p + 1]) + fabsf(wb2 - xv[p + 2]);
      }
    }
  }

  // --- Phase E: reduce the 16 cq-partials per (filter, col) through LDS ---
  #pragma unroll
  for (int p = 0; p < 28; ++p) {
    Rbuf[(cq * 32 + fl) * 29 + p] = acc0[p];
    Rbuf[(cq * 32 + fl + 16) * 29 + p] = acc1[p];
  }
  __syncthreads();

  // 896 outputs (32 f x 28 cols) / 256 threads
  #pragma unroll
  for (int i = 0; i < 4; ++i) {
    int idx = tid + 256 * i;
    if (idx < 896) {
      int ff = idx / 28, col = idx - ff * 28;
      float s = 0.0f;
      #pragma unroll
      for (int q = 0; q < 16; ++q) s += Rbuf[(q * 32 + ff) * 29 + col];
      out[((n * 64 + fh * 32 + ff) * 28 + y) * 28 + col] = -s;
    }
  }
}

extern "C" void kernel_launch(void* const* d_in, const int* in_sizes, int n_in,
                              void* d_out, int out_size, void* d_ws, size_t ws_size,
                              hipStream_t stream) {
  const float* x  = (const float*)d_in[0];
  const float* Wg = (const float*)d_in[1];
  float* out = (float*)d_out;
  float* ws  = (float*)d_ws;

  hipLaunchKernelGGL(k_prep, dim3(64), dim3(256), 0, stream, x, Wg, ws);
  hipLaunchKernelGGL(k_main, dim3(28, 4, 2), dim3(256), 0, stream, x, ws, out);
}

// Round 6
// 73.688 us; speedup vs baseline: 1.6985x; 1.0936x over previous
//
#include <hip/hip_runtime.h>
#include <math.h>

// Problem constants (fixed shapes from reference)
#define N_  4
#define C_  64
#define H_  28
#define W_  28
#define F_  64
#define KK  576            // C_ * 3 * 3
#define NX  (N_*C_*H_*W_)  // 200704
#define NX4 (NX/4)         // 50176 float4s

#define XCH 52             // Xs floats per channel: 3 rows x 16 + 4 pad.
                           // 52 % 32 == 20 -> the 4 per-wave channel bases hit
                           // disjoint bank quads (0,20,8,28 / 16,4,24,12).

// ws float layout:
// [0..63]    per-block partial min of x
// [64..127]  per-block partial max of x
// [256..]    Wt[576*64]  dequantized W, k-major: Wt[(c*9+k)*64 + f]

// ---------------------------------------------------------------------------
// Kernel 1: grid 64 x 256.
//   All blocks: partial min/max of x (float4).
//   Blocks 0..15 additionally: fake-quant+dequant 4 filters (1 per wave),
//   write k-major Wt into ws.
// ---------------------------------------------------------------------------
__global__ __launch_bounds__(256) void k_prep(const float* __restrict__ x,
                                              const float* __restrict__ Wg,
                                              float* __restrict__ ws) {
  __shared__ float sm[4], sM[4];
  int tid = threadIdx.x, lane = tid & 63, wv = tid >> 6;

  const float4* x4 = (const float4*)x;
  float m = 3.4e38f, M = -3.4e38f;
  for (int i = blockIdx.x * 256 + tid; i < NX4; i += 64 * 256) {
    float4 v = x4[i];
    m = fminf(m, fminf(fminf(v.x, v.y), fminf(v.z, v.w)));
    M = fmaxf(M, fmaxf(fmaxf(v.x, v.y), fmaxf(v.z, v.w)));
  }
  #pragma unroll
  for (int o = 32; o; o >>= 1) {
    m = fminf(m, __shfl_xor(m, o));
    M = fmaxf(M, __shfl_xor(M, o));
  }
  if (lane == 0) { sm[wv] = m; sM[wv] = M; }
  __syncthreads();
  if (tid == 0) {
    m = fminf(fminf(sm[0], sm[1]), fminf(sm[2], sm[3]));
    M = fmaxf(fmaxf(sM[0], sM[1]), fmaxf(sM[2], sM[3]));
    ws[blockIdx.x] = m;
    ws[64 + blockIdx.x] = M;
  }

  if (blockIdx.x < 16) {
    int f = blockIdx.x * 4 + wv;
    const float* wp = Wg + f * KK;
    float v[9];
    float wm = 3.4e38f, wM = -3.4e38f;
    #pragma unroll
    for (int u = 0; u < 9; ++u) {
      v[u] = wp[lane + 64 * u];
      wm = fminf(wm, v[u]);
      wM = fmaxf(wM, v[u]);
    }
    #pragma unroll
    for (int o = 32; o; o >>= 1) {
      wm = fminf(wm, __shfl_xor(wm, o));
      wM = fmaxf(wM, __shfl_xor(wM, o));
    }
    float s = fmaxf((wM - wm) / 255.0f, 1e-12f);
    float z = rintf(-wm / s);
    float rs = 1.0f / s;
    float* Wt = ws + 256;
    #pragma unroll
    for (int u = 0; u < 9; ++u) {
      float q = fminf(fmaxf(rintf(v[u] * rs) + z, 0.0f), 255.0f);
      Wt[(lane + 64 * u) * 64 + f] = (q - z) * s;
    }
  }
}

// ---------------------------------------------------------------------------
// Kernel 2: grid (y=28, n=4, z=4: fh = z>>1, colh = z&1) = 448 blocks (~2/CU).
//   Block: 32 filters (fh) x 14 output cols (colh), ALL 64 channels.
//   Thread (fl in 0..15, cq in 0..15): filters f0 = fh*32+fl, f1 = f0+16;
//   channels c = cq + 16*ci; 14 cols. W from L2 (prefetched), X from LDS.
//   44 KB LDS -> 2 blocks/CU co-resident: waves finally overlap.
// ---------------------------------------------------------------------------
__global__ __launch_bounds__(256, 2) void k_main(const float* __restrict__ x,
                                                 const float* __restrict__ ws,
                                                 float* __restrict__ out) {
  __shared__ __align__(16) float Xs[64 * XCH];      // 13.3 KB quantized x slab
  __shared__ float Rbuf[16 * 32 * 15];              // 30 KB [cq][f_local][col pad 15]
  int tid = threadIdx.x;
  int lane = tid & 63;
  int fl = tid & 15, cq = tid >> 4;
  int y = blockIdx.x, n = blockIdx.y;
  int fh = blockIdx.z >> 1, colh = blockIdx.z & 1;
  int bc = colh * 14;                               // first output col of this block

  // --- Phase A: x scale/zp (register butterfly, no barrier) ---
  float m = ws[lane], M = ws[64 + lane];
  #pragma unroll
  for (int o = 32; o; o >>= 1) {
    m = fminf(m, __shfl_xor(m, o));
    M = fmaxf(M, __shfl_xor(M, o));
  }
  float sx = fmaxf((M - m) / 65535.0f, 1e-12f);
  float zx = rintf(-m / sx);
  float rx = 1.0f / sx;

  // --- Phase B: stage quantized X, 64 ch x 3 rows x 16 cols (bc-1 .. bc+14) ---
  {
    int j = tid & 15, sub = tid >> 4;               // 16 (c,r) pairs per pass
    #pragma unroll
    for (int it = 0; it < 12; ++it) {
      int cr = sub + 16 * it;                       // 0..191
      int c = cr / 3, r = cr - c * 3;
      int row = y + r - 1, col = bc - 1 + j;
      float v = 0.0f;
      if ((unsigned)row < 28u && (unsigned)col < 28u) {
        float raw = x[((n * 64 + c) * 28 + row) * 28 + col];
        float q = fminf(fmaxf(rintf(raw * rx) + zx, 0.0f), 65535.0f);
        v = (q - zx) * sx;
      }
      Xs[c * XCH + r * 16 + j] = v;
    }
  }
  __syncthreads();

  // --- Phase C: main loop ---
  const float* Wt = ws + 256;
  int f0 = fh * 32 + fl;                            // second filter = f0 + 16
  float acc0[14], acc1[14];
  #pragma unroll
  for (int i = 0; i < 14; ++i) { acc0[i] = 0.0f; acc1[i] = 0.0f; }

  float wc[18], wn[18];
  {
    const float* wp = Wt + (cq * 9) * 64 + f0;
    #pragma unroll
    for (int k = 0; k < 9; ++k) { wn[k] = wp[k * 64]; wn[9 + k] = wp[k * 64 + 16]; }
  }

  for (int ci = 0; ci < 4; ++ci) {
    #pragma unroll
    for (int k = 0; k < 18; ++k) wc[k] = wn[k];
    if (ci < 3) {
      const float* wp = Wt + ((cq + 16 * (ci + 1)) * 9) * 64 + f0;
      #pragma unroll
      for (int k = 0; k < 9; ++k) { wn[k] = wp[k * 64]; wn[9 + k] = wp[k * 64 + 16]; }
    }
    int c = cq + 16 * ci;
    #pragma unroll
    for (int r = 0; r < 3; ++r) {
      const float4* xr4 = (const float4*)&Xs[c * XCH + r * 16];
      float xv[16];
      #pragma unroll
      for (int i = 0; i < 4; ++i) ((float4*)xv)[i] = xr4[i];
      float wa0 = wc[3 * r], wa1 = wc[3 * r + 1], wa2 = wc[3 * r + 2];
      float wb0 = wc[9 + 3 * r], wb1 = wc[9 + 3 * r + 1], wb2 = wc[9 + 3 * r + 2];
      #pragma unroll
      for (int p = 0; p < 14; ++p) {
        acc0[p] += fabsf(wa0 - xv[p]) + fabsf(wa1 - xv[p + 1]) + fabsf(wa2 - xv[p + 2]);
        acc1[p] += fabsf(wb0 - xv[p]) + fabsf(wb1 - xv[p + 1]) + fabsf(wb2 - xv[p + 2]);
      }
    }
  }

  // --- Phase E: write 16 cq-partials, one barrier, gather ---
  #pragma unroll
  for (int p = 0; p < 14; ++p) {
    Rbuf[(cq * 32 + fl) * 15 + p]      = acc0[p];
    Rbuf[(cq * 32 + 16 + fl) * 15 + p] = acc1[p];
  }
  __syncthreads();

  // 448 outputs (32 f x 14 cols) / 256 threads
  #pragma unroll
  for (int i = 0; i < 2; ++i) {
    int idx = tid + 256 * i;
    if (idx < 448) {
      int ff = idx / 14, col = idx - ff * 14;
      float s = 0.0f;
      #pragma unroll
      for (int q = 0; q < 16; ++q) s += Rbuf[(q * 32 + ff) * 15 + col];
      out[((n * 64 + fh * 32 + ff) * 28 + y) * 28 + bc + col] = -s;
    }
  }
}

extern "C" void kernel_launch(void* const* d_in, const int* in_sizes, int n_in,
                              void* d_out, int out_size, void* d_ws, size_t ws_size,
                              hipStream_t stream) {
  const float* x  = (const float*)d_in[0];
  const float* Wg = (const float*)d_in[1];
  float* out = (float*)d_out;
  float* ws  = (float*)d_ws;

  hipLaunchKernelGGL(k_prep, dim3(64), dim3(256), 0, stream, x, Wg, ws);
  hipLaunchKernelGGL(k_main, dim3(28, 4, 4), dim3(256), 0, stream, x, ws, out);
}